// Round 5
// baseline (40.927 us; speedup 1.0000x reference)
//
#include <hip/hip_runtime.h>
#include <hip/hip_bf16.h>
#include <math.h>

#define NPIX 65536

typedef short short8 __attribute__((ext_vector_type(8)));
typedef float f32x4 __attribute__((ext_vector_type(4)));

// ---- static device scratch (fully rewritten every call) ----
__device__ unsigned long long g_cand[4096];
__device__ int            g_kp_idx[2048];
__device__ float          g_invws[2048];
__device__ float          g_nnws[2048];
__device__ __hip_bfloat16 g_dbf[2048 * 192];   // all descriptors, bf16
__device__ __hip_bfloat16 g_dw0[1024 * 192];   // side-1 desc * fc_w[0,:], bf16
__device__ __hip_bfloat16 g_dw1[1024 * 192];   // side-1 desc * fc_w[1,:], bf16

__device__ __forceinline__ unsigned long long u64min(unsigned long long a, unsigned long long b) {
    return a < b ? a : b;
}
__device__ __forceinline__ unsigned long long u64max(unsigned long long a, unsigned long long b) {
    return a > b ? a : b;
}

// ---------------- phase 1a: window max (full-chip, logit domain) ----------
// grid 1024 x 256 threads; wave w of block handles window blk*4+w; lane = pixel.
__global__ __launch_bounds__(256) void winmax_kernel(
        const float* __restrict__ hm1, const float* __restrict__ hm2) {
    int wid  = blockIdx.x * 4 + (threadIdx.x >> 6);   // 0..4095
    int lane = threadIdx.x & 63;
    int img  = wid >> 10;                             // hm*2 + b
    int win  = wid & 1023;
    int b = img & 1;
    const float* hp = ((img >> 1) ? hm2 : hm1) + b * NPIX;
    int wy = win >> 5, wx = win & 31;
    int py = wy * 8 + (lane >> 3);
    int px = wx * 8 + (lane & 7);
    int fidx = py * 256 + px;
    float mv = hp[fidx];
    int mi = fidx;
    // wave max on raw logits, earliest-index tie-break
    #pragma unroll
    for (int m = 1; m <= 32; m <<= 1) {
        float ov = __shfl_xor(mv, m);
        int   oi = __shfl_xor(mi, m);
        if (ov > mv || (ov == mv && oi < mi)) { mv = ov; mi = oi; }
    }
    if (lane == 0) {
        int ay = mi >> 8, ax = mi & 255;
        bool interior = (ay >= 10 && ay < 246 && ax >= 10 && ax < 246);
        unsigned int ub = __float_as_uint(mv);
        unsigned int mk = (ub & 0x80000000u) ? ~ub : (ub | 0x80000000u);
        if (!interior) mk = 0u;
        // ascending sort key: smallest = largest value, ties -> smallest idx
        g_cand[wid] = ((unsigned long long)(~mk) << 32) |
                      (unsigned long long)(unsigned int)mi;
    }
}

// ---------------- phase 1b: top-512 bitonic sort (keys from L2) ----------
// grid 4 x 1024 threads; strides<=32 via shfl, >=64 via LDS.
__global__ __launch_bounds__(1024) void topk_kernel(float* __restrict__ out) {
    __shared__ unsigned long long keys[1024];
    int img = blockIdx.x;
    int t = threadIdx.x;
    int b = img & 1, hmid = img >> 1;
    unsigned long long k = g_cand[img * 1024 + t];

    for (int size = 2; size <= 1024; size <<= 1) {
        for (int stride = size >> 1; stride >= 1; stride >>= 1) {
            bool dir_up = ((t & size) == 0);
            unsigned long long pk;
            if (stride >= 64) {
                __syncthreads();
                keys[t] = k;
                __syncthreads();
                pk = keys[t ^ stride];
            } else {
                pk = __shfl_xor(k, stride);
            }
            bool low = ((t & stride) == 0);
            k = ((low == dir_up)) ? u64min(k, pk) : u64max(k, pk);
        }
    }

    if (t < 512) {
        unsigned int fidx = (unsigned int)(k & 0xFFFFFFFFull);
        unsigned int mk2 = ~(unsigned int)(k >> 32);
        unsigned int lb = (mk2 & 0x80000000u) ? (mk2 ^ 0x80000000u) : ~mk2;
        float logit = __uint_as_float(lb);
        float v = 1.0f / (1.0f + expf(-logit));
        int row = fidx >> 8, col = fidx & 255;
        float gx = 2.0f * (float)col / 255.0f - 1.0f;
        float gy = 2.0f * (float)row / 255.0f - 1.0f;
        out[hmid * 1024 + b * 512 + t] = v;
        float* lm = out + (hmid ? 4096 : 2048) + (size_t)(b * 512 + t) * 2;
        lm[0] = gx; lm[1] = gy;
        g_kp_idx[img * 512 + t] = (int)fidx;
    }
}

// ---------------- phase 2: descriptor gather + norm + bf16 prep ----------
// grid 2048 x 192 threads; one THREAD per (keypoint, channel) -> 24 waves/CU
// of outstanding scattered loads. Border guarantees interior bilinear.
__global__ void desc_kernel(
        const float* __restrict__ f1a, const float* __restrict__ f1b,
        const float* __restrict__ f2a, const float* __restrict__ f2b,
        const float* __restrict__ fcw) {
    __shared__ float part[3];
    int kp = blockIdx.x;                     // 0..2047
    int c = threadIdx.x;                     // 0..191
    int img = kp >> 9, b = img & 1, hmid = img >> 1;
    int fidx = g_kp_idx[kp];
    int row = fidx >> 8, col = fidx & 255;

    float val;
    if (c < 64) {
        // full-res half: exact pixel -> direct gather
        const float* fa = (hmid ? f2a : f1a) + (size_t)(b * 64 + c) * 65536;
        val = fa[fidx];
    } else {
        // half-res: bilinear, replicate reference arithmetic exactly
        float gx = 2.0f * (float)col / 255.0f - 1.0f;
        float gy = 2.0f * (float)row / 255.0f - 1.0f;
        float ix = (gx + 1.0f) * 0.5f * 127.0f;
        float iy = (gy + 1.0f) * 0.5f * 127.0f;
        int x0 = (int)ix, y0 = (int)iy;      // interior: trunc == floor
        float wx = ix - (float)x0, wy = iy - (float)y0;
        const float* fb0 = (hmid ? f2b : f1b) + (size_t)(b * 128 + (c - 64)) * 16384
                           + y0 * 128 + x0;
        float v00 = fb0[0], v01 = fb0[1], v10 = fb0[128], v11 = fb0[129];
        val = v00 * (1 - wx) * (1 - wy) + v01 * wx * (1 - wy)
            + v10 * (1 - wx) * wy       + v11 * wx * wy;
    }

    g_dbf[(size_t)kp * 192 + c] = __float2bfloat16(val);
    if (kp < 1024) {
        g_dw0[(size_t)kp * 192 + c] = __float2bfloat16(val * fcw[c]);
        g_dw1[(size_t)kp * 192 + c] = __float2bfloat16(val * fcw[192 + c]);
    }

    float sq = val * val;
    #pragma unroll
    for (int m = 1; m <= 32; m <<= 1) sq += __shfl_xor(sq, m);
    if ((threadIdx.x & 63) == 0) part[threadIdx.x >> 6] = sq;
    __syncthreads();
    if (threadIdx.x == 0) {
        float ss = part[0] + part[1] + part[2];
        float nrm = sqrtf(ss);
        float inv = 1.0f / (1e-6f + nrm);
        g_invws[kp] = inv;
        g_nnws[kp] = ss * inv * inv;   // ||n||^2
    }
}

// ---------------- phase 3: pairwise matching via MFMA --------------------
// C = D1 * D2^T with three accumulator sets (dot, score0, score1).
// grid (8, 32, 2) x 256 thr; one wave per 16x16 output tile; no LDS.
__global__ __launch_bounds__(256) void match_kernel(
        const float* __restrict__ fcb, float* __restrict__ out) {
    int t = threadIdx.x;
    int w = t >> 6, lane = t & 63;
    int b = blockIdx.z;
    int k1base = blockIdx.y * 16;
    int k2base = blockIdx.x * 64 + w * 16;
    int r1 = k1base + (lane & 15);
    int r2 = k2base + (lane & 15);
    int koff = (lane >> 4) * 8;

    const __hip_bfloat16* pA  = g_dbf + (size_t)(b * 512 + r1) * 192 + koff;
    const __hip_bfloat16* pW0 = g_dw0 + (size_t)(b * 512 + r1) * 192 + koff;
    const __hip_bfloat16* pW1 = g_dw1 + (size_t)(b * 512 + r1) * 192 + koff;
    const __hip_bfloat16* pB  = g_dbf + (size_t)((2 + b) * 512 + r2) * 192 + koff;

    f32x4 accd = {0.f, 0.f, 0.f, 0.f};
    f32x4 acc0 = {0.f, 0.f, 0.f, 0.f};
    f32x4 acc1 = {0.f, 0.f, 0.f, 0.f};
    #pragma unroll
    for (int kc = 0; kc < 6; ++kc) {
        short8 a  = *reinterpret_cast<const short8*>(pA  + kc * 32);
        short8 a0 = *reinterpret_cast<const short8*>(pW0 + kc * 32);
        short8 a1 = *reinterpret_cast<const short8*>(pW1 + kc * 32);
        short8 bb = *reinterpret_cast<const short8*>(pB  + kc * 32);
        accd = __builtin_amdgcn_mfma_f32_16x16x32_bf16(a,  bb, accd, 0, 0, 0);
        acc0 = __builtin_amdgcn_mfma_f32_16x16x32_bf16(a0, bb, acc0, 0, 0, 0);
        acc1 = __builtin_amdgcn_mfma_f32_16x16x32_bf16(a1, bb, acc1, 0, 0, 0);
    }

    float bb0 = fcb[0], bb1 = fcb[1];
    int colc = lane & 15;
    int k2 = k2base + colc;
    float inv2 = g_invws[(2 + b) * 512 + k2];
    float nn2  = g_nnws[(2 + b) * 512 + k2];
    #pragma unroll
    for (int j = 0; j < 4; ++j) {
        int k1 = k1base + (lane >> 4) * 4 + j;
        float inv1 = g_invws[b * 512 + k1];
        float nn1  = g_nnws[b * 512 + k1];
        size_t sidx = (size_t)(b * 512 + k1) * 512 + k2;
        float2 sc = make_float2(acc0[j] + bb0, acc1[j] + bb1);
        *reinterpret_cast<float2*>(out + 6144 + sidx * 2) = sc;
        float arg = nn1 + nn2 - 2.0f * inv1 * inv2 * accd[j];
        out[1054720 + sidx] = sqrtf(fmaxf(arg, 0.0f));
    }
}

extern "C" void kernel_launch(void* const* d_in, const int* in_sizes, int n_in,
                              void* d_out, int out_size, void* d_ws, size_t ws_size,
                              hipStream_t stream) {
    const float* hm1 = (const float*)d_in[0];
    const float* hm2 = (const float*)d_in[1];
    const float* f1a = (const float*)d_in[2];
    const float* f1b = (const float*)d_in[3];
    const float* f2a = (const float*)d_in[4];
    const float* f2b = (const float*)d_in[5];
    const float* fcw = (const float*)d_in[6];
    const float* fcb = (const float*)d_in[7];
    float* out = (float*)d_out;
    (void)d_ws; (void)ws_size;

    winmax_kernel<<<1024, 256, 0, stream>>>(hm1, hm2);
    topk_kernel<<<4, 1024, 0, stream>>>(out);
    desc_kernel<<<2048, 192, 0, stream>>>(f1a, f1b, f2a, f2b, fcw);
    dim3 g(8, 32, 2);
    match_kernel<<<g, 256, 0, stream>>>(fcb, out);
}